// Round 10
// baseline (316.907 us; speedup 1.0000x reference)
//
#include <hip/hip_runtime.h>
#include <math.h>

#define T_ 4096
#define D_ 512
#define H_ 2048
#define E_ 16

typedef short bf16x8 __attribute__((ext_vector_type(8)));
typedef float f32x4 __attribute__((ext_vector_type(4)));

__device__ __forceinline__ unsigned short f2bf(float f) {
  union { float f; unsigned u; } v; v.f = f;
  unsigned r = v.u + 0x7fffu + ((v.u >> 16) & 1u);
  return (unsigned short)(r >> 16);
}
__device__ __forceinline__ float bf2f(unsigned short u) {
  union { unsigned u; float f; } v; v.u = ((unsigned)u) << 16;
  return v.f;
}
// async global->LDS, 16B per lane; lds dest = wave-uniform base + lane*16 (m97/m104)
__device__ __forceinline__ void gload_lds16(const unsigned short* g, unsigned short* l) {
  __builtin_amdgcn_global_load_lds((const __attribute__((address_space(1))) void*)g,
                                   (__attribute__((address_space(3))) void*)l, 16, 0, 0);
}
// tanh-form gelu = x * sigmoid(2s). NaN-free.
__device__ __forceinline__ float gelu_fast(float y) {
  float s2 = 1.5957691216f * (y + 0.044715f * y * y * y);
  return y * __builtin_amdgcn_rcpf(1.f + __expf(-s2));
}

// -------- weight convert+transpose one 64x64 tile: [E][K][N] f32 -> [E][N][K] bf16
template <int K, int N>
__device__ __forceinline__ void wtrans_tile(const float* __restrict__ src,
                                            unsigned short* __restrict__ dst,
                                            int e, int n0, int k0, int tid,
                                            unsigned short (*tile)[72]) {
  const int tr = tid >> 4, tc = (tid & 15) << 2;
  const float* s = src + ((size_t)e * K + k0) * N + n0;
#pragma unroll
  for (int p = 0; p < 4; ++p) {
    float4 v = *(const float4*)(s + (size_t)(tr + p * 16) * N + tc);
    tile[tc + 0][tr + p * 16] = f2bf(v.x);
    tile[tc + 1][tr + p * 16] = f2bf(v.y);
    tile[tc + 2][tr + p * 16] = f2bf(v.z);
    tile[tc + 3][tr + p * 16] = f2bf(v.w);
  }
  __syncthreads();
  const int wr = tid >> 2, wc = (tid & 3) << 4;
  unsigned short* d = dst + ((size_t)e * N + n0 + wr) * K + k0 + wc;
  *(uint4*)d       = *(const uint4*)&tile[wr][wc];
  *(uint4*)(d + 8) = *(const uint4*)&tile[wr][wc + 8];
  __syncthreads();
}

// =========== K1: gate || wtrans1 (horizontal fusion, disjoint block ranges) ===========
__global__ __launch_bounds__(256) void gate_wt1(
    const float* __restrict__ x, const float* __restrict__ Wg,
    const float* __restrict__ bg, const float* __restrict__ W1,
    float* __restrict__ out, int* __restrict__ tok2e,
    int* __restrict__ cnt2, unsigned short* __restrict__ Wt) {
  __shared__ float wgl[D_ * E_];  // 32 KB (gate weights / wtrans tile union)
  const int bid = blockIdx.x;
  const int tid = threadIdx.x;
  if (bid < 1024) {
    unsigned short (*tile)[72] = (unsigned short (*)[72])wgl;
#pragma unroll
    for (int p = 0; p < 4; ++p) {
      const int tt = bid + (p << 10);            // 0..4095
      const int we = tt >> 8, rem = tt & 255;    // 32 n-tiles x 8 k-tiles per expert
      wtrans_tile<D_, H_>(W1, Wt, we, (rem & 31) << 6, (rem >> 5) << 6, tid, tile);
    }
    return;
  }
  // ---- gate ----
  if (bid == 1024 && tid < E_ * 16) cnt2[tid] = 0;
  for (int i = tid; i < D_ * E_ / 4; i += 256)
    *(float4*)&wgl[i * 4] = ((const float4*)Wg)[i];
  __syncthreads();
  const int lane = tid & 63;
  const int t = (bid - 1024) * 4 + (tid >> 6);
  const int e = lane & 15, q = lane >> 4;
  const float4* x4 = (const float4*)(x + (size_t)t * D_ + q * 128);
  float acc = 0.f;
#pragma unroll 4
  for (int i = 0; i < 32; ++i) {
    float4 v = x4[i];
    const float* wp = &wgl[(q * 128 + i * 4) * E_ + e];
    acc += v.x * wp[0];
    acc += v.y * wp[E_];
    acc += v.z * wp[2 * E_];
    acc += v.w * wp[3 * E_];
  }
  acc += __shfl_xor(acc, 16);
  acc += __shfl_xor(acc, 32);
  const float logit = acc + bg[e];
  float v1 = logit; int i1 = e;
#pragma unroll
  for (int s = 1; s < 16; s <<= 1) {
    float ov = __shfl_xor(v1, s); int oi = __shfl_xor(i1, s);
    if (ov > v1 || (ov == v1 && oi < i1)) { v1 = ov; i1 = oi; }
  }
  float v2 = (e == i1) ? -INFINITY : logit; int i2 = e;
#pragma unroll
  for (int s = 1; s < 16; s <<= 1) {
    float ov = __shfl_xor(v2, s); int oi = __shfl_xor(i2, s);
    if (ov > v2 || (ov == v2 && oi < i2)) { v2 = ov; i2 = oi; }
  }
  if (lane == 0) {
    const float ed = __expf(v2 - v1);
    const float inv = 1.f / (1.f + ed);
    const size_t gidx = (size_t)T_ * D_;
    out[gidx + t * 2]     = (float)i1;
    out[gidx + t * 2 + 1] = (float)i2;
    out[gidx + T_ * 2 + t * 2]     = inv;
    out[gidx + T_ * 2 + t * 2 + 1] = ed * inv;
    tok2e[t * 2] = i1; tok2e[t * 2 + 1] = i2;
  }
}

// =========== K2: scatter-gather with in-block recount ===========
__global__ __launch_bounds__(256) void scatgath_kernel(
    const float* __restrict__ x, const int* __restrict__ tok2e,
    int* __restrict__ cnt2, int* __restrict__ tok2row,
    unsigned short* __restrict__ xg, int* __restrict__ ntiles,
    int* __restrict__ tile2e, int* __restrict__ tile2row0) {
  __shared__ int wsh[4][E_];
  __shared__ int hsh[E_];
  const int tid = threadIdx.x, lane = tid & 63, wv = tid >> 6;
  // private histogram (static indices only -> registers, rule #20)
  int c[E_];
#pragma unroll
  for (int e = 0; e < E_; ++e) c[e] = 0;
  for (int i = tid; i < 2 * T_; i += 256) {
    const int v = tok2e[i];
#pragma unroll
    for (int e = 0; e < E_; ++e) c[e] += (v == e) ? 1 : 0;
  }
#pragma unroll
  for (int e = 0; e < E_; ++e) {
#pragma unroll
    for (int s = 1; s < 64; s <<= 1) c[e] += __shfl_xor(c[e], s);
  }
  if (lane == 0) {
#pragma unroll
    for (int e = 0; e < E_; ++e) wsh[wv][e] = c[e];
  }
  __syncthreads();
  if (tid < E_) hsh[tid] = wsh[0][tid] + wsh[1][tid] + wsh[2][tid] + wsh[3][tid];
  __syncthreads();
  // block 0: tile tables for the GEMMs (<=80 M-tiles total)
  if (blockIdx.x == 0 && tid == 0) {
    int o = 0, to = 0;
    for (int ee = 0; ee < E_; ++ee) {
      const int mt = (hsh[ee] + 127) >> 7;
      for (int i = 0; i < mt; ++i) { tile2e[to + i] = ee; tile2row0[to + i] = o + (i << 7); }
      o += mt << 7; to += mt;
    }
    ntiles[0] = to;
  }
  // scatter: one wave per token, writes both xg rows
  const int t = blockIdx.x * 4 + wv;
  int rA = 0, rB = 0;
  if (lane == 0) {
    const int e1 = tok2e[t * 2], e2 = tok2e[t * 2 + 1];
    int o = 0, oA = 0, oB = 0;
#pragma unroll
    for (int i = 0; i < E_; ++i) {
      if (i == e1) oA = o;
      if (i == e2) oB = o;
      o += ((hsh[i] + 127) >> 7) << 7;
    }
    rA = oA + atomicAdd(&cnt2[e1 * 16], 1);
    rB = oB + atomicAdd(&cnt2[e2 * 16], 1);
    tok2row[t * 2] = rA; tok2row[t * 2 + 1] = rB;
  }
  rA = __shfl(rA, 0); rB = __shfl(rB, 0);
  const float4* p = (const float4*)(x + (size_t)t * D_ + lane * 8);
  const float4 a = p[0], b = p[1];
  const unsigned w0 = f2bf(a.x) | (f2bf(a.y) << 16);
  const unsigned w1 = f2bf(a.z) | (f2bf(a.w) << 16);
  const unsigned w2 = f2bf(b.x) | (f2bf(b.y) << 16);
  const unsigned w3 = f2bf(b.z) | (f2bf(b.w) << 16);
  const uint4 val = make_uint4(w0, w1, w2, w3);
  *(uint4*)(xg + (size_t)rA * D_ + lane * 8) = val;
  *(uint4*)(xg + (size_t)rB * D_ + lane * 8) = val;
}

// =========== K4: wtrans2 — W2 [E][2048][512] f32 -> Wt [E][512][2048] bf16 ===========
__global__ __launch_bounds__(256) void wt2_kernel(const float* __restrict__ W2,
                                                  unsigned short* __restrict__ Wt) {
  __shared__ unsigned short tile[64][72];
#pragma unroll
  for (int p = 0; p < 4; ++p) {
    const int tt = blockIdx.x + (p << 10);       // 0..4095
    const int we = tt >> 8, rem = tt & 255;      // 8 n-tiles x 32 k-tiles per expert
    wtrans_tile<H_, D_>(W2, Wt, we, (rem & 7) << 6, (rem >> 3) << 6, threadIdx.x, tile);
  }
}

// ===== K3/K5: tiled bf16 MFMA GEMM (R5/R9-proven body), HALF-N dispatches =====
// NSPAN = N range covered by this dispatch (n0base..n0base+NSPAN). Splitting each
// GEMM into two half-N dispatches tiers the durations (~22 µs each) so the
// never-yet-profiled kernels (gate_wt1/wt2/scatgath/combine) surface in the
// rocprof top-5 — R10 is a measurement round (boundaries measured free in R9).
// 8 waves / 512 threads; double-buffered LDS, ONE __syncthreads per K-step.
// LDS tiles UNPADDED [rows][64]; XOR swizzle of 16B column-blocks.
// T1 bijective XCD swizzle, N-fastest within dispatch (FETCH 86->39 MB, R3).
template <int KDIM, int NTOT, int NSPAN, int NTILE, bool GELU>
__global__ __launch_bounds__(512, 4) void ffn_gemm(
    const unsigned short* __restrict__ A_g, const unsigned short* __restrict__ Bt_g,
    const float* __restrict__ bias_g, unsigned short* __restrict__ out_g,
    const int* __restrict__ ntiles, const int* __restrict__ tile2e,
    const int* __restrict__ tile2row0, int n0base) {
  constexpr int JN = NTILE / 64;                 // b-fragments per wave (2 or 1)
  constexpr int BRPW = NTILE / 8;                // B rows staged per wave (16 or 8)
  constexpr int NK = KDIM / 64;                  // K-steps
  constexpr int NBN = NSPAN / NTILE;             // N-tiles this dispatch (8 or 4)
  constexpr int NBLK = 80 * NBN;                 // launched blocks (640/320), %8==0
  __shared__ unsigned short As[2 * 128 * 64];    // 32 KB (double-buffered)
  __shared__ unsigned short Bs[2 * NTILE * 64];  // 32 or 16 KB
  const int lid = blockIdx.x;
  const int swz = (lid & 7) * (NBLK >> 3) + (lid >> 3);
  const int mt = swz / NBN;
  const int n0 = n0base + (swz % NBN) * NTILE;
  if (mt >= ntiles[0]) return;
  const int e = tile2e[mt];
  const int row0 = tile2row0[mt];
  const int tid = threadIdx.x;
  const int lane = tid & 63;
  const int w = tid >> 6;                        // 0..7
  const int m_off = (w >> 2) << 6;               // 0 or 64
  const int n_off = (w & 3) * (NTILE / 4);       // quarter columns

  f32x4 acc[4][JN];
#pragma unroll
  for (int i = 0; i < 4; ++i)
#pragma unroll
    for (int j = 0; j < JN; ++j) acc[i][j] = (f32x4){0.f, 0.f, 0.f, 0.f};

  const int r_in = lane >> 3;
  const int cbg = (lane & 7) ^ r_in;
  const unsigned short* gA = A_g + (size_t)(row0 + w * 16 + r_in) * KDIM + cbg * 8;
  const unsigned short* gB = Bt_g + ((size_t)e * NTOT + n0 + w * BRPW + r_in) * KDIM + cbg * 8;
  const int q = lane >> 4, fr = lane & 15;

  auto stage = [&](int half, int k0) {
    unsigned short* lA = &As[half * (128 * 64) + w * 16 * 64];
    unsigned short* lB = &Bs[half * (NTILE * 64) + w * BRPW * 64];
#pragma unroll
    for (int j = 0; j < 2; ++j)
      gload_lds16(gA + (size_t)j * 8 * KDIM + k0, lA + j * 8 * 64);
#pragma unroll
    for (int j = 0; j < BRPW / 8; ++j)
      gload_lds16(gB + (size_t)j * 8 * KDIM + k0, lB + j * 8 * 64);
  };

  stage(0, 0);
  __syncthreads();  // implicit vmcnt(0): tile 0 staged

#pragma unroll 2
  for (int t = 0; t < NK; ++t) {
    const int cur = t & 1;
    if (t + 1 < NK) stage(cur ^ 1, (t + 1) * 64);  // prefetch next tile
    const unsigned short* cA = &As[cur * (128 * 64)];
    const unsigned short* cB = &Bs[cur * (NTILE * 64)];
#pragma unroll
    for (int kk = 0; kk < 64; kk += 32) {
      bf16x8 af[4], bfr[JN];
#pragma unroll
      for (int i = 0; i < 4; ++i) {
        const int r = m_off + i * 16 + fr;
        const int sw = ((((kk >> 3) + q) ^ (r & 7)) << 3);
        af[i] = *(const bf16x8*)&cA[r * 64 + sw];
      }
#pragma unroll
      for (int j = 0; j < JN; ++j) {
        const int r = n_off + j * 16 + fr;
        const int sw = ((((kk >> 3) + q) ^ (r & 7)) << 3);
        bfr[j] = *(const bf16x8*)&cB[r * 64 + sw];
      }
#pragma unroll
      for (int i = 0; i < 4; ++i)
#pragma unroll
        for (int j = 0; j < JN; ++j)
          acc[i][j] = __builtin_amdgcn_mfma_f32_16x16x32_bf16(af[i], bfr[j], acc[i][j], 0, 0, 0);
    }
    __syncthreads();  // drains prefetch (vmcnt 0) + all waves done reading cur
  }

  // epilogue: C/D layout col=lane&15, row=quad*4+reg (m89); LDS bounce for
  // coalesced stores, 16B blocks XOR-swizzled by (row & (LB-1)).
  constexpr int W = NTILE / 4;   // cols per wave (32 or 16)
  constexpr int LB = W / 8;      // 16B blocks per row (4 or 2)
  unsigned short* cbase = &As[w * 64 * W];
  const float* bias = bias_g + (size_t)e * NTOT;
#pragma unroll
  for (int j = 0; j < JN; ++j) {
    const float bv = bias[n0 + n_off + j * 16 + fr];
#pragma unroll
    for (int i = 0; i < 4; ++i) {
      f32x4 v = acc[i][j];
#pragma unroll
      for (int r = 0; r < 4; ++r) {
        float y = v[r] + bv;
        if (GELU) y = gelu_fast(y);
        const int lr = i * 16 + (q << 2) + r;
        const int lc = j * 16 + fr;
        const int phys = (lc >> 3) ^ (lr & (LB - 1));
        cbase[lr * W + phys * 8 + (lc & 7)] = f2bf(y);
      }
    }
  }
  __syncthreads();  // order LDS writes before cross-lane readback
#pragma unroll
  for (int it = 0; it < LB; ++it) {
    const int lr = it * (64 / LB) + (lane / LB);
    const int bl = lane % LB;
    const int phys = bl ^ (lr & (LB - 1));
    const uint4 val = *(const uint4*)&cbase[lr * W + phys * 8];
    *(uint4*)&out_g[(size_t)(row0 + m_off + lr) * NTOT + n0 + n_off + bl * 8] = val;
  }
}

// =========== K6: combine (8 tokens/block, one per wave; 512 x 512) ===========
__global__ __launch_bounds__(512) void combine_kernel(
    const unsigned short* __restrict__ ybuf, const int* __restrict__ tok2row,
    float* __restrict__ out) {
  const int lane = threadIdx.x & 63;
  const int t = blockIdx.x * 8 + (threadIdx.x >> 6);
  const int rA = tok2row[t * 2], rB = tok2row[t * 2 + 1];
  const uint4 va = *(const uint4*)(ybuf + (size_t)rA * D_ + lane * 8);
  const uint4 vb = *(const uint4*)(ybuf + (size_t)rB * D_ + lane * 8);
  const unsigned short* pa = (const unsigned short*)&va;
  const unsigned short* pb = (const unsigned short*)&vb;
  float o[8];
#pragma unroll
  for (int i = 0; i < 8; ++i) o[i] = bf2f(pa[i]) + bf2f(pb[i]);
  float4* po = (float4*)(out + (size_t)t * D_ + lane * 8);
  po[0] = make_float4(o[0], o[1], o[2], o[3]);
  po[1] = make_float4(o[4], o[5], o[6], o[7]);
}

extern "C" void kernel_launch(void* const* d_in, const int* in_sizes, int n_in,
                              void* d_out, int out_size, void* d_ws, size_t ws_size,
                              hipStream_t stream) {
  const float* x  = (const float*)d_in[0];
  const float* Wg = (const float*)d_in[1];
  const float* bg = (const float*)d_in[2];
  const float* W1 = (const float*)d_in[3];
  const float* b1 = (const float*)d_in[4];
  const float* W2 = (const float*)d_in[5];
  const float* b2 = (const float*)d_in[6];
  float* out = (float*)d_out;
  char* ws = (char*)d_ws;

  // ws layout (84 MB):
  int* cnt2      = (int*)(ws);               // 16 experts x 16-int stride
  int* ntiles    = (int*)(ws + 2112);
  int* tile2e    = (int*)(ws + 2176);        // 96 ints
  int* tile2row0 = (int*)(ws + 2560);        // 96 ints
  int* tok2e     = (int*)(ws + 4096);        // 8192 ints
  int* tok2row   = (int*)(ws + 4096 + 32768);
  unsigned short* xg   = (unsigned short*)(ws + (1 << 20));           // 10 MB
  unsigned short* ybuf = xg;                                          // reuse after GEMM1
  unsigned short* hbuf = (unsigned short*)(ws + (size_t)(12 << 20));  // 40 MB
  unsigned short* Wt   = (unsigned short*)(ws + (size_t)(52 << 20));  // 32 MB (W1t, then W2t)

  // K1: gate || wtrans1 (horizontal fusion; block 1024 zeros cnt2)
  gate_wt1<<<2048, 256, 0, stream>>>(x, Wg, bg, W1, out, tok2e, cnt2, Wt);
  // K2: recount + tables + scatter-gather
  scatgath_kernel<<<T_ / 4, 256, 0, stream>>>(x, tok2e, cnt2, tok2row, xg,
                                              ntiles, tile2e, tile2row0);
  // K3a/K3b: GEMM1 in two half-N dispatches (K=512, N=2048, NTILE=128)
  ffn_gemm<512, 2048, 1024, 128, true><<<640, 512, 0, stream>>>(
      xg, Wt, b1, hbuf, ntiles, tile2e, tile2row0, 0);
  ffn_gemm<512, 2048, 1024, 128, true><<<640, 512, 0, stream>>>(
      xg, Wt, b1, hbuf, ntiles, tile2e, tile2row0, 1024);
  // K4: wtrans2 (reuses Wt slot; stream-ordered after GEMM1)
  wt2_kernel<<<1024, 256, 0, stream>>>(W2, Wt);
  // K5a/K5b: GEMM2 in two half-N dispatches (K=2048, N=512, NTILE=64)
  ffn_gemm<2048, 512, 256, 64, false><<<320, 512, 0, stream>>>(
      hbuf, Wt, b2, ybuf, ntiles, tile2e, tile2row0, 0);
  ffn_gemm<2048, 512, 256, 64, false><<<320, 512, 0, stream>>>(
      hbuf, Wt, b2, ybuf, ntiles, tile2e, tile2row0, 256);
  // K6: combine
  combine_kernel<<<512, 512, 0, stream>>>(ybuf, tok2row, out);
}

// Round 11
// 281.196 us; speedup vs baseline: 1.1270x; 1.1270x over previous
//
#include <hip/hip_runtime.h>
#include <math.h>

#define T_ 4096
#define D_ 512
#define H_ 2048
#define E_ 16

typedef short bf16x8 __attribute__((ext_vector_type(8)));
typedef float f32x4 __attribute__((ext_vector_type(4)));

__device__ __forceinline__ unsigned short f2bf(float f) {
  union { float f; unsigned u; } v; v.f = f;
  unsigned r = v.u + 0x7fffu + ((v.u >> 16) & 1u);
  return (unsigned short)(r >> 16);
}
__device__ __forceinline__ float bf2f(unsigned short u) {
  union { unsigned u; float f; } v; v.u = ((unsigned)u) << 16;
  return v.f;
}
// async global->LDS, 16B per lane; lds dest = wave-uniform base + lane*16 (m97/m104)
__device__ __forceinline__ void gload_lds16(const unsigned short* g, unsigned short* l) {
  __builtin_amdgcn_global_load_lds((const __attribute__((address_space(1))) void*)g,
                                   (__attribute__((address_space(3))) void*)l, 16, 0, 0);
}
// tanh-form gelu = x * sigmoid(2s). NaN-free.
__device__ __forceinline__ float gelu_fast(float y) {
  float s2 = 1.5957691216f * (y + 0.044715f * y * y * y);
  return y * __builtin_amdgcn_rcpf(1.f + __expf(-s2));
}

// -------- weight convert+transpose one 64x64 tile: [E][K][N] f32 -> [E][N][K] bf16
// R11: column XOR-swizzle in 8-short (16B) granules keyed on row>>2 breaks the
// 8-way write conflict measured in R10 (SQ_LDS_BANK_CONFLICT 4.85M on gate_wt1:
// transpose writes put lanes i,i+2 on the same bank at stride 144 dwords).
// 16B granule preserves uint4 contiguity+alignment on the read side.
template <int K, int N>
__device__ __forceinline__ void wtrans_tile(const float* __restrict__ src,
                                            unsigned short* __restrict__ dst,
                                            int e, int n0, int k0, int tid,
                                            unsigned short (*tile)[72]) {
  const int tr = tid >> 4, tc = (tid & 15) << 2;
  const int sw = ((tc >> 2) & 7) << 3;   // rows tc..tc+3 share row>>2 = tc>>2
  const float* s = src + ((size_t)e * K + k0) * N + n0;
#pragma unroll
  for (int p = 0; p < 4; ++p) {
    float4 v = *(const float4*)(s + (size_t)(tr + p * 16) * N + tc);
    const int c = (tr + p * 16) ^ sw;
    tile[tc + 0][c] = f2bf(v.x);
    tile[tc + 1][c] = f2bf(v.y);
    tile[tc + 2][c] = f2bf(v.z);
    tile[tc + 3][c] = f2bf(v.w);
  }
  __syncthreads();
  const int wr = tid >> 2, wc = (tid & 3) << 4;
  const int rsw = ((wr >> 2) & 7) << 3;
  unsigned short* d = dst + ((size_t)e * N + n0 + wr) * K + k0 + wc;
  *(uint4*)d       = *(const uint4*)&tile[wr][wc ^ rsw];
  *(uint4*)(d + 8) = *(const uint4*)&tile[wr][(wc + 8) ^ rsw];
  __syncthreads();
}

// =========== K1: gate || wtrans1 (horizontal fusion, disjoint block ranges) ===========
__global__ __launch_bounds__(256) void gate_wt1(
    const float* __restrict__ x, const float* __restrict__ Wg,
    const float* __restrict__ bg, const float* __restrict__ W1,
    float* __restrict__ out, int* __restrict__ tok2e,
    int* __restrict__ cnt2, unsigned short* __restrict__ Wt) {
  __shared__ float wgl[D_ * E_];  // 32 KB (gate weights / wtrans tile union)
  const int bid = blockIdx.x;
  const int tid = threadIdx.x;
  if (bid < 1024) {
    unsigned short (*tile)[72] = (unsigned short (*)[72])wgl;
#pragma unroll
    for (int p = 0; p < 4; ++p) {
      const int tt = bid + (p << 10);            // 0..4095
      const int we = tt >> 8, rem = tt & 255;    // 32 n-tiles x 8 k-tiles per expert
      wtrans_tile<D_, H_>(W1, Wt, we, (rem & 31) << 6, (rem >> 5) << 6, tid, tile);
    }
    return;
  }
  // ---- gate ----
  if (bid == 1024 && tid < E_ * 16) cnt2[tid] = 0;
  for (int i = tid; i < D_ * E_ / 4; i += 256)
    *(float4*)&wgl[i * 4] = ((const float4*)Wg)[i];
  __syncthreads();
  const int lane = tid & 63;
  const int t = (bid - 1024) * 4 + (tid >> 6);
  const int e = lane & 15, q = lane >> 4;
  const float4* x4 = (const float4*)(x + (size_t)t * D_ + q * 128);
  float acc = 0.f;
#pragma unroll 4
  for (int i = 0; i < 32; ++i) {
    float4 v = x4[i];
    const float* wp = &wgl[(q * 128 + i * 4) * E_ + e];
    acc += v.x * wp[0];
    acc += v.y * wp[E_];
    acc += v.z * wp[2 * E_];
    acc += v.w * wp[3 * E_];
  }
  acc += __shfl_xor(acc, 16);
  acc += __shfl_xor(acc, 32);
  const float logit = acc + bg[e];
  float v1 = logit; int i1 = e;
#pragma unroll
  for (int s = 1; s < 16; s <<= 1) {
    float ov = __shfl_xor(v1, s); int oi = __shfl_xor(i1, s);
    if (ov > v1 || (ov == v1 && oi < i1)) { v1 = ov; i1 = oi; }
  }
  float v2 = (e == i1) ? -INFINITY : logit; int i2 = e;
#pragma unroll
  for (int s = 1; s < 16; s <<= 1) {
    float ov = __shfl_xor(v2, s); int oi = __shfl_xor(i2, s);
    if (ov > v2 || (ov == v2 && oi < i2)) { v2 = ov; i2 = oi; }
  }
  if (lane == 0) {
    const float ed = __expf(v2 - v1);
    const float inv = 1.f / (1.f + ed);
    const size_t gidx = (size_t)T_ * D_;
    out[gidx + t * 2]     = (float)i1;
    out[gidx + t * 2 + 1] = (float)i2;
    out[gidx + T_ * 2 + t * 2]     = inv;
    out[gidx + T_ * 2 + t * 2 + 1] = ed * inv;
    tok2e[t * 2] = i1; tok2e[t * 2 + 1] = i2;
  }
}

// =========== K2: scatter-gather with in-block recount ===========
__global__ __launch_bounds__(256) void scatgath_kernel(
    const float* __restrict__ x, const int* __restrict__ tok2e,
    int* __restrict__ cnt2, int* __restrict__ tok2row,
    unsigned short* __restrict__ xg, int* __restrict__ ntiles,
    int* __restrict__ tile2e, int* __restrict__ tile2row0) {
  __shared__ int wsh[4][E_];
  __shared__ int hsh[E_];
  const int tid = threadIdx.x, lane = tid & 63, wv = tid >> 6;
  // private histogram (static indices only -> registers, rule #20)
  int c[E_];
#pragma unroll
  for (int e = 0; e < E_; ++e) c[e] = 0;
  for (int i = tid; i < 2 * T_; i += 256) {
    const int v = tok2e[i];
#pragma unroll
    for (int e = 0; e < E_; ++e) c[e] += (v == e) ? 1 : 0;
  }
#pragma unroll
  for (int e = 0; e < E_; ++e) {
#pragma unroll
    for (int s = 1; s < 64; s <<= 1) c[e] += __shfl_xor(c[e], s);
  }
  if (lane == 0) {
#pragma unroll
    for (int e = 0; e < E_; ++e) wsh[wv][e] = c[e];
  }
  __syncthreads();
  if (tid < E_) hsh[tid] = wsh[0][tid] + wsh[1][tid] + wsh[2][tid] + wsh[3][tid];
  __syncthreads();
  // block 0: tile tables for the GEMMs (<=80 M-tiles total)
  if (blockIdx.x == 0 && tid == 0) {
    int o = 0, to = 0;
    for (int ee = 0; ee < E_; ++ee) {
      const int mt = (hsh[ee] + 127) >> 7;
      for (int i = 0; i < mt; ++i) { tile2e[to + i] = ee; tile2row0[to + i] = o + (i << 7); }
      o += mt << 7; to += mt;
    }
    ntiles[0] = to;
  }
  // scatter: one wave per token, writes both xg rows
  const int t = blockIdx.x * 4 + wv;
  int rA = 0, rB = 0;
  if (lane == 0) {
    const int e1 = tok2e[t * 2], e2 = tok2e[t * 2 + 1];
    int o = 0, oA = 0, oB = 0;
#pragma unroll
    for (int i = 0; i < E_; ++i) {
      if (i == e1) oA = o;
      if (i == e2) oB = o;
      o += ((hsh[i] + 127) >> 7) << 7;
    }
    rA = oA + atomicAdd(&cnt2[e1 * 16], 1);
    rB = oB + atomicAdd(&cnt2[e2 * 16], 1);
    tok2row[t * 2] = rA; tok2row[t * 2 + 1] = rB;
  }
  rA = __shfl(rA, 0); rB = __shfl(rB, 0);
  const float4* p = (const float4*)(x + (size_t)t * D_ + lane * 8);
  const float4 a = p[0], b = p[1];
  const unsigned w0 = f2bf(a.x) | (f2bf(a.y) << 16);
  const unsigned w1 = f2bf(a.z) | (f2bf(a.w) << 16);
  const unsigned w2 = f2bf(b.x) | (f2bf(b.y) << 16);
  const unsigned w3 = f2bf(b.z) | (f2bf(b.w) << 16);
  const uint4 val = make_uint4(w0, w1, w2, w3);
  *(uint4*)(xg + (size_t)rA * D_ + lane * 8) = val;
  *(uint4*)(xg + (size_t)rB * D_ + lane * 8) = val;
}

// =========== K4: wtrans2 — W2 [E][2048][512] f32 -> Wt [E][512][2048] bf16 ===========
__global__ __launch_bounds__(256) void wt2_kernel(const float* __restrict__ W2,
                                                  unsigned short* __restrict__ Wt) {
  __shared__ unsigned short tile[64][72];
#pragma unroll
  for (int p = 0; p < 4; ++p) {
    const int tt = blockIdx.x + (p << 10);       // 0..4095
    const int we = tt >> 8, rem = tt & 255;      // 8 n-tiles x 32 k-tiles per expert
    wtrans_tile<H_, D_>(W2, Wt, we, (rem & 7) << 6, (rem >> 3) << 6, threadIdx.x, tile);
  }
}

// ===== K3/K5: tiled bf16 MFMA GEMM (R5/R9-proven body; full-N dispatches) =====
// 8 waves / 512 threads; per-wave output 64 x NTILE/4. Double-buffered LDS, ONE
// __syncthreads per K-step (race-free protocol, harness-verified R5/R9). LDS
// tiles UNPADDED [rows][64]; XOR swizzle of 16B column-blocks (stage & read
// agree). T1 bijective XCD swizzle, N-fastest (FETCH 86->39 MB measured R3).
// R10's half-N split REVERTED: it cost ~35 µs (extra drains + duplicated
// A-staging + tails) and was only a measurement device.
template <int KDIM, int NTOT, int NTILE, bool GELU>
__global__ __launch_bounds__(512, 4) void ffn_gemm(
    const unsigned short* __restrict__ A_g, const unsigned short* __restrict__ Bt_g,
    const float* __restrict__ bias_g, unsigned short* __restrict__ out_g,
    const int* __restrict__ ntiles, const int* __restrict__ tile2e,
    const int* __restrict__ tile2row0) {
  constexpr int JN = NTILE / 64;                 // b-fragments per wave (2 or 1)
  constexpr int BRPW = NTILE / 8;                // B rows staged per wave (16 or 8)
  constexpr int NK = KDIM / 64;                  // K-steps
  constexpr int NBN = NTOT / NTILE;              // N-tiles (16 or 8)
  constexpr int NBLK = 80 * NBN;                 // launched blocks, %8==0
  __shared__ unsigned short As[2 * 128 * 64];    // 32 KB (double-buffered)
  __shared__ unsigned short Bs[2 * NTILE * 64];  // 32 or 16 KB
  const int lid = blockIdx.x;
  const int swz = (lid & 7) * (NBLK >> 3) + (lid >> 3);
  const int mt = swz / NBN;
  const int n0 = (swz % NBN) * NTILE;
  if (mt >= ntiles[0]) return;
  const int e = tile2e[mt];
  const int row0 = tile2row0[mt];
  const int tid = threadIdx.x;
  const int lane = tid & 63;
  const int w = tid >> 6;                        // 0..7
  const int m_off = (w >> 2) << 6;               // 0 or 64
  const int n_off = (w & 3) * (NTILE / 4);       // quarter columns

  f32x4 acc[4][JN];
#pragma unroll
  for (int i = 0; i < 4; ++i)
#pragma unroll
    for (int j = 0; j < JN; ++j) acc[i][j] = (f32x4){0.f, 0.f, 0.f, 0.f};

  const int r_in = lane >> 3;
  const int cbg = (lane & 7) ^ r_in;
  const unsigned short* gA = A_g + (size_t)(row0 + w * 16 + r_in) * KDIM + cbg * 8;
  const unsigned short* gB = Bt_g + ((size_t)e * NTOT + n0 + w * BRPW + r_in) * KDIM + cbg * 8;
  const int q = lane >> 4, fr = lane & 15;

  auto stage = [&](int half, int k0) {
    unsigned short* lA = &As[half * (128 * 64) + w * 16 * 64];
    unsigned short* lB = &Bs[half * (NTILE * 64) + w * BRPW * 64];
#pragma unroll
    for (int j = 0; j < 2; ++j)
      gload_lds16(gA + (size_t)j * 8 * KDIM + k0, lA + j * 8 * 64);
#pragma unroll
    for (int j = 0; j < BRPW / 8; ++j)
      gload_lds16(gB + (size_t)j * 8 * KDIM + k0, lB + j * 8 * 64);
  };

  stage(0, 0);
  __syncthreads();  // implicit vmcnt(0): tile 0 staged

#pragma unroll 2
  for (int t = 0; t < NK; ++t) {
    const int cur = t & 1;
    if (t + 1 < NK) stage(cur ^ 1, (t + 1) * 64);  // prefetch next tile
    const unsigned short* cA = &As[cur * (128 * 64)];
    const unsigned short* cB = &Bs[cur * (NTILE * 64)];
#pragma unroll
    for (int kk = 0; kk < 64; kk += 32) {
      bf16x8 af[4], bfr[JN];
#pragma unroll
      for (int i = 0; i < 4; ++i) {
        const int r = m_off + i * 16 + fr;
        const int sw = ((((kk >> 3) + q) ^ (r & 7)) << 3);
        af[i] = *(const bf16x8*)&cA[r * 64 + sw];
      }
#pragma unroll
      for (int j = 0; j < JN; ++j) {
        const int r = n_off + j * 16 + fr;
        const int sw = ((((kk >> 3) + q) ^ (r & 7)) << 3);
        bfr[j] = *(const bf16x8*)&cB[r * 64 + sw];
      }
#pragma unroll
      for (int i = 0; i < 4; ++i)
#pragma unroll
        for (int j = 0; j < JN; ++j)
          acc[i][j] = __builtin_amdgcn_mfma_f32_16x16x32_bf16(af[i], bfr[j], acc[i][j], 0, 0, 0);
    }
    __syncthreads();  // drains prefetch (vmcnt 0) + all waves done reading cur
  }

  // epilogue: C/D layout col=lane&15, row=quad*4+reg (m89); LDS bounce for
  // coalesced stores, 16B blocks XOR-swizzled by (row & (LB-1)).
  constexpr int W = NTILE / 4;   // cols per wave (32 or 16)
  constexpr int LB = W / 8;      // 16B blocks per row (4 or 2)
  unsigned short* cbase = &As[w * 64 * W];
  const float* bias = bias_g + (size_t)e * NTOT;
#pragma unroll
  for (int j = 0; j < JN; ++j) {
    const float bv = bias[n0 + n_off + j * 16 + fr];
#pragma unroll
    for (int i = 0; i < 4; ++i) {
      f32x4 v = acc[i][j];
#pragma unroll
      for (int r = 0; r < 4; ++r) {
        float y = v[r] + bv;
        if (GELU) y = gelu_fast(y);
        const int lr = i * 16 + (q << 2) + r;
        const int lc = j * 16 + fr;
        const int phys = (lc >> 3) ^ (lr & (LB - 1));
        cbase[lr * W + phys * 8 + (lc & 7)] = f2bf(y);
      }
    }
  }
  __syncthreads();  // order LDS writes before cross-lane readback
#pragma unroll
  for (int it = 0; it < LB; ++it) {
    const int lr = it * (64 / LB) + (lane / LB);
    const int bl = lane % LB;
    const int phys = bl ^ (lr & (LB - 1));
    const uint4 val = *(const uint4*)&cbase[lr * W + phys * 8];
    *(uint4*)&out_g[(size_t)(row0 + m_off + lr) * NTOT + n0 + n_off + bl * 8] = val;
  }
}

// =========== K6: combine (8 tokens/block, one per wave; 512 x 512) ===========
__global__ __launch_bounds__(512) void combine_kernel(
    const unsigned short* __restrict__ ybuf, const int* __restrict__ tok2row,
    float* __restrict__ out) {
  const int lane = threadIdx.x & 63;
  const int t = blockIdx.x * 8 + (threadIdx.x >> 6);
  const int rA = tok2row[t * 2], rB = tok2row[t * 2 + 1];
  const uint4 va = *(const uint4*)(ybuf + (size_t)rA * D_ + lane * 8);
  const uint4 vb = *(const uint4*)(ybuf + (size_t)rB * D_ + lane * 8);
  const unsigned short* pa = (const unsigned short*)&va;
  const unsigned short* pb = (const unsigned short*)&vb;
  float o[8];
#pragma unroll
  for (int i = 0; i < 8; ++i) o[i] = bf2f(pa[i]) + bf2f(pb[i]);
  float4* po = (float4*)(out + (size_t)t * D_ + lane * 8);
  po[0] = make_float4(o[0], o[1], o[2], o[3]);
  po[1] = make_float4(o[4], o[5], o[6], o[7]);
}

extern "C" void kernel_launch(void* const* d_in, const int* in_sizes, int n_in,
                              void* d_out, int out_size, void* d_ws, size_t ws_size,
                              hipStream_t stream) {
  const float* x  = (const float*)d_in[0];
  const float* Wg = (const float*)d_in[1];
  const float* bg = (const float*)d_in[2];
  const float* W1 = (const float*)d_in[3];
  const float* b1 = (const float*)d_in[4];
  const float* W2 = (const float*)d_in[5];
  const float* b2 = (const float*)d_in[6];
  float* out = (float*)d_out;
  char* ws = (char*)d_ws;

  // ws layout (84 MB):
  int* cnt2      = (int*)(ws);               // 16 experts x 16-int stride
  int* ntiles    = (int*)(ws + 2112);
  int* tile2e    = (int*)(ws + 2176);        // 96 ints
  int* tile2row0 = (int*)(ws + 2560);        // 96 ints
  int* tok2e     = (int*)(ws + 4096);        // 8192 ints
  int* tok2row   = (int*)(ws + 4096 + 32768);
  unsigned short* xg   = (unsigned short*)(ws + (1 << 20));           // 10 MB
  unsigned short* ybuf = xg;                                          // reuse after GEMM1
  unsigned short* hbuf = (unsigned short*)(ws + (size_t)(12 << 20));  // 40 MB
  unsigned short* Wt   = (unsigned short*)(ws + (size_t)(52 << 20));  // 32 MB (W1t, then W2t)

  // K1: gate || wtrans1 (horizontal fusion; block 1024 zeros cnt2)
  gate_wt1<<<2048, 256, 0, stream>>>(x, Wg, bg, W1, out, tok2e, cnt2, Wt);
  // K2: recount + tables + scatter-gather
  scatgath_kernel<<<T_ / 4, 256, 0, stream>>>(x, tok2e, cnt2, tok2row, xg,
                                              ntiles, tile2e, tile2row0);
  // K3: GEMM1  h = gelu(xg @ W1t + b1) -> hbuf   (K=512, N=2048, NTILE=128)
  ffn_gemm<512, 2048, 128, true><<<1280, 512, 0, stream>>>(
      xg, Wt, b1, hbuf, ntiles, tile2e, tile2row0);
  // K4: wtrans2 (reuses Wt slot; stream-ordered after GEMM1)
  wt2_kernel<<<1024, 256, 0, stream>>>(W2, Wt);
  // K5: GEMM2  y = hbuf @ W2t + b2 -> ybuf       (K=2048, N=512, NTILE=64)
  ffn_gemm<2048, 512, 64, false><<<640, 512, 0, stream>>>(
      hbuf, Wt, b2, ybuf, ntiles, tile2e, tile2row0);
  // K6: combine
  combine_kernel<<<512, 512, 0, stream>>>(ybuf, tok2row, out);
}